// Round 3
// baseline (41.262 us; speedup 1.0000x reference)
//
#include <hip/hip_runtime.h>

#define NN 128
#define CCH 16
#define BB 4
#define HID 128
#define DOUT 128

// One block = (b, row p). 512 threads = 8 waves. Grid 512 = 2 blocks/CU.
// Phase 1: thread (cq = t>>7, q = t&127) runs the 4->128->2 MLP for
//          c in {cq, cq+4, cq+8, cq+12}: h1 -> s_out, h0 -> diag reduction.
//          Weights read via wave-uniform (scalar) loads — no LDS in k-loop.
// Phase 2: wave wv handles d = wv*16 .. wv*16+15 (wave-uniform -> scalar Wc),
//          lane covers m as float2. ReLU + streamed store.
__global__ __launch_bounds__(512, 4) void fused_rey(
    const float* __restrict__ x, const float* __restrict__ W1,
    const float* __restrict__ b1, const float* __restrict__ W2,
    const float* __restrict__ b2, const float* __restrict__ Wc,
    const float* __restrict__ bc, float* __restrict__ y)
{
    __shared__ float s_out[CCH][NN];   // 8 KB: one out-row per channel
    __shared__ float s_part[8][4];     // per-wave diag partials

    const int t   = threadIdx.x;
    const int bid = blockIdx.x;
    const int p   = bid & 127;
    const int b   = bid >> 7;
    const int q   = t & 127;
    const int cq  = t >> 7;            // 0..3
    const int wv  = t >> 6;            // 0..7

    const float bb0 = b2[0], bb1 = b2[1];

    // ---- per-thread x loads: 4 channels c = cq + 4j ----
    float x_pp[4], x_pq[4], x_qp[4], x_qq[4];
    #pragma unroll
    for (int j = 0; j < 4; ++j) {
        const int c = cq + 4 * j;
        const float* xm = x + ((size_t)(b * CCH + c) << 14);
        x_pp[j] = xm[p * (NN + 1)];    // wave-uniform -> scalar load
        x_pq[j] = xm[p * NN + q];      // coalesced row read
        x_qp[j] = xm[q * NN + p];      // strided (column) read
        x_qq[j] = xm[q * (NN + 1)];    // strided (diagonal) read
    }

    float h0[4], h1[4];
    #pragma unroll
    for (int j = 0; j < 4; ++j) { h0[j] = bb0; h1[j] = bb1; }

    // ---- phase 1: hidden loop, weights from scalar loads ----
    #pragma unroll 4
    for (int k = 0; k < HID; ++k) {
        const float4 w  = reinterpret_cast<const float4*>(W1)[k];
        const float b1k = b1[k];
        const float w20 = W2[k];
        const float w21 = W2[HID + k];
        #pragma unroll
        for (int j = 0; j < 4; ++j) {
            float hd = fmaf(w.x, x_pp[j], b1k);
            hd = fmaf(w.y, x_pq[j], hd);
            hd = fmaf(w.z, x_qp[j], hd);
            hd = fmaf(w.w, x_qq[j], hd);
            hd = fmaxf(hd, 0.f);
            h0[j] = fmaf(w20, hd, h0[j]);
            h1[j] = fmaf(w21, hd, h1[j]);
        }
    }

    // ---- write off-diagonal h1; exclude q==p from diag sum ----
    #pragma unroll
    for (int j = 0; j < 4; ++j) {
        const int c = cq + 4 * j;
        s_out[c][q] = h1[j];           // (p,p) slot fixed below
        if (q == p) h0[j] = 0.f;
    }

    // ---- diag: wave shuffle-reduce, then cross-wave combine ----
    #pragma unroll
    for (int j = 0; j < 4; ++j) {
        float v = h0[j];
        for (int off = 32; off > 0; off >>= 1)
            v += __shfl_down(v, off, 64);
        if ((t & 63) == 0) s_part[wv][j] = v;
    }
    __syncthreads();
    if (t < 16) {
        const int cq2 = t >> 2, j2 = t & 3;
        const int c2 = cq2 + 4 * j2;
        s_out[c2][p] = (s_part[2 * cq2][j2] + s_part[2 * cq2 + 1][j2])
                       * (1.0f / (NN - 1));
    }
    __syncthreads();

    // ---- phase 2: y[b,d,p,:] = relu(sum_c s_out[c]*Wc[d][c] + bc[d]) ----
    const int lane = t & 63;
    const int m0 = lane * 2;
    float2 r[CCH];
    #pragma unroll
    for (int c = 0; c < CCH; ++c)
        r[c] = *reinterpret_cast<const float2*>(&s_out[c][m0]);

    #pragma unroll
    for (int dd = 0; dd < 16; ++dd) {
        const int d = wv * 16 + dd;            // wave-uniform
        const float bcv = bc[d];               // scalar load
        float2 acc = { bcv, bcv };
        #pragma unroll
        for (int c = 0; c < CCH; ++c) {
            const float wcv = Wc[d * CCH + c]; // scalar load
            acc.x = fmaf(wcv, r[c].x, acc.x);
            acc.y = fmaf(wcv, r[c].y, acc.y);
        }
        acc.x = fmaxf(acc.x, 0.f);
        acc.y = fmaxf(acc.y, 0.f);
        float* yp = y + ((((size_t)(b * DOUT + d)) * NN + p) * NN + m0);
        *reinterpret_cast<float2*>(yp) = acc;
    }
}

extern "C" void kernel_launch(void* const* d_in, const int* in_sizes, int n_in,
                              void* d_out, int out_size, void* d_ws, size_t ws_size,
                              hipStream_t stream) {
    const float* x  = (const float*)d_in[0];
    const float* W1 = (const float*)d_in[1];
    const float* b1 = (const float*)d_in[2];
    const float* W2 = (const float*)d_in[3];
    const float* b2 = (const float*)d_in[4];
    const float* Wc = (const float*)d_in[5];
    const float* bc = (const float*)d_in[6];
    float* y = (float*)d_out;

    dim3 grid(BB * NN);   // 512 blocks = 2 per CU, 16 waves/CU
    fused_rey<<<grid, 512, 0, stream>>>(x, W1, b1, W2, b2, Wc, bc, y);
}